// Round 3
// baseline (320.769 us; speedup 1.0000x reference)
//
#include <hip/hip_runtime.h>

// TSP_GNN: 2x GCNConv(edge-weighted, self-loops) + FC + row softmax.
// N=8192 nodes, E=262144 edges, H=64.
// R3: gemm1 rewritten for occupancy: 4 waves x 16 rows (no LDS, no cross-wave
// reduce), K split across 8 blocks -> 1024 blocks (4/CU), partials + k_red.

#define NN 8192
#define NE 262144
#define HD 64
#define KCH 1024   // K-chunk per gemm1 block
#define NKC 8      // number of K-chunks

typedef float f32x4 __attribute__((ext_vector_type(4)));
typedef short v8s   __attribute__((ext_vector_type(8)));
typedef unsigned short ushort_t;

__device__ __forceinline__ unsigned short bf16_rne(float f){
  union { float f; unsigned u; } v; v.f = f;
  unsigned r = v.u + 0x7fffu + ((v.u >> 16) & 1u);
  return (unsigned short)(r >> 16);
}
__device__ __forceinline__ float bf16_f32(unsigned short h){
  union { unsigned u; float f; } v; v.u = ((unsigned)h) << 16;
  return v.f;
}
__device__ __forceinline__ f32x4 mfma16(v8s a, v8s b, f32x4 c){
  return __builtin_amdgcn_mfma_f32_16x16x32_bf16(a, b, c, 0, 0, 0);
}

// ---------------- prep: init + pack W1 (hi/lo) + pack fcW ----------------
// W1 [8192][64]: idx = ((kb*4+nt)*16+c)*32+kk  (k=kb*32+kk, col=nt*16+c)
// fcW [64][8192]: idx = ((kb*512+cblk)*16+c)*32+kk (k=kb*32+kk, col=cblk*16+c)
__global__ void k_prep0(const float* __restrict__ W1, const float* __restrict__ fcW,
                        ushort_t* w1hi, ushort_t* w1lo, ushort_t* fcwp,
                        float* deg, int* cnt, int* wcnt, float* S){
  int idx = blockIdx.x*blockDim.x + threadIdx.x;   // 0..524287
  if (idx < NN){ deg[idx]=1.0f; cnt[idx]=0; wcnt[idx]=0; S[idx]=0.0f; }
  {
    int kk = idx & 31, c = (idx>>5)&15, nt = (idx>>9)&3, kb = idx>>11;
    int k = kb*32 + kk, col = nt*16 + c;
    float w = W1[(size_t)k*HD + col];
    unsigned short hi = bf16_rne(w);
    w1hi[idx] = hi;
    w1lo[idx] = bf16_rne(w - bf16_f32(hi));
  }
  {
    int kk = idx & 31, c = (idx>>5)&15, cblk = (idx>>9)&511, kb = idx>>18;
    int k = kb*32 + kk, col = cblk*16 + c;
    fcwp[idx] = bf16_rne(fcW[(size_t)k*NN + col]);
  }
}

__global__ void k_deg_cnt(const int* ei, const float* ew, float* deg, int* cnt){
  int e = blockIdx.x*blockDim.x + threadIdx.x;
  if (e < NE){
    int d = ei[NE + e];                 // dst
    atomicAdd(&deg[d], ew[e]);
    atomicAdd(&cnt[d], 1);
  }
}

// single-block: exclusive scan of counts -> rowptr, plus dinv = 1/sqrt(deg)
__global__ void k_scan(const int* cnt, const float* deg, int* rowptr, float* dinv){
  __shared__ int part[256];
  int t = threadIdx.x;
  int loc[32]; int s = 0;
  #pragma unroll
  for (int j=0;j<32;++j){ loc[j] = cnt[t*32+j]; s += loc[j]; }
  part[t] = s; __syncthreads();
  for (int off=1; off<256; off<<=1){
    int v = (t >= off) ? part[t-off] : 0;
    __syncthreads();
    part[t] += v;
    __syncthreads();
  }
  int run = part[t] - s;
  #pragma unroll
  for (int j=0;j<32;++j){ rowptr[t*32+j] = run; run += loc[j]; }
  if (t == 255) rowptr[NN] = run;
  #pragma unroll
  for (int j=0;j<32;++j) dinv[t*32+j] = 1.0f / sqrtf(deg[t*32+j]);
}

__global__ void k_fill(const int* ei, const float* ew, const float* dinv,
                       const int* rowptr, int* wcnt, int* csr_src, float* csr_nrm){
  int e = blockIdx.x*blockDim.x + threadIdx.x;
  if (e < NE){
    int s = ei[e], d = ei[NE+e];
    int slot = rowptr[d] + atomicAdd(&wcnt[d], 1);
    csr_src[slot] = s;
    csr_nrm[slot] = dinv[s] * ew[e] * dinv[d];
  }
}

// ---------------- GEMM1: xw1p[kc] = X[:, kc] @ W1[kc, :] ----------------
// block = 256 thr (4 waves), wave owns 16 rows x KCH; no LDS, no reduction.
// grid = (128 row-tiles, NKC k-chunks) = 1024 blocks -> 4 blocks/CU.
__global__ __launch_bounds__(256) void k_gemm1(const float* __restrict__ X,
                                               const ushort_t* __restrict__ w1hi,
                                               const ushort_t* __restrict__ w1lo,
                                               float* __restrict__ xw1p){
  int lane = threadIdx.x & 63, w = threadIdx.x >> 6;
  int r = lane & 15, seg = lane >> 4;
  int row = blockIdx.x*64 + w*16 + r;
  int kb0 = blockIdx.y * KCH;
  const float* xr = X + (size_t)row * NN + kb0 + seg*8;

  f32x4 z = {0.f,0.f,0.f,0.f};
  f32x4 acc[4] = {z,z,z,z};

  f32x4 p0 = *(const f32x4*)(xr);
  f32x4 p1 = *(const f32x4*)(xr + 4);

  for (int it = 0; it < KCH/32; ++it){
    f32x4 c0 = p0, c1 = p1;
    if (it < KCH/32 - 1){
      p0 = *(const f32x4*)(xr + (it+1)*32);
      p1 = *(const f32x4*)(xr + (it+1)*32 + 4);
    }
    v8s ah, al;
    #pragma unroll
    for (int j=0;j<4;++j){
      float f = c0[j]; unsigned short h = bf16_rne(f);
      ah[j] = (short)h; al[j] = (short)bf16_rne(f - bf16_f32(h));
      f = c1[j]; h = bf16_rne(f);
      ah[4+j] = (short)h; al[4+j] = (short)bf16_rne(f - bf16_f32(h));
    }
    int kbb = (kb0 >> 5) + it;
    #pragma unroll
    for (int nt=0; nt<4; ++nt){
      size_t boff = ((size_t)(kbb*4 + nt)*16 + r)*32 + seg*8;
      v8s bh = *(const v8s*)(w1hi + boff);
      v8s bl = *(const v8s*)(w1lo + boff);
      acc[nt] = mfma16(ah, bh, acc[nt]);
      acc[nt] = mfma16(ah, bl, acc[nt]);
      acc[nt] = mfma16(al, bh, acc[nt]);
    }
  }

  // D layout: row-within-16 = 4*seg+j, col = nt*16+r
  float* o = xw1p + (size_t)blockIdx.y*(NN*HD) + (size_t)(blockIdx.x*64 + w*16)*HD;
  #pragma unroll
  for (int nt=0; nt<4; ++nt)
    #pragma unroll
    for (int j=0;j<4;++j)
      o[(4*seg + j)*HD + nt*16 + r] = acc[nt][j];
}

// reduce NKC partial planes -> xw1
__global__ __launch_bounds__(256) void k_red(const float* __restrict__ xw1p,
                                             float* __restrict__ xw1){
  int i = blockIdx.x*blockDim.x + threadIdx.x;   // over NN*HD/4
  f32x4 s = {0.f,0.f,0.f,0.f};
  #pragma unroll
  for (int c=0;c<NKC;++c){
    f32x4 v = *(const f32x4*)(xw1p + (size_t)c*NN*HD + (size_t)i*4);
    s[0]+=v[0]; s[1]+=v[1]; s[2]+=v[2]; s[3]+=v[3];
  }
  *(f32x4*)(xw1 + (size_t)i*4) = s;
}

// ---------------- agg1 + conv2 fused ----------------
__global__ __launch_bounds__(256) void k_agg1c(const float* __restrict__ xin,
                                               const float* __restrict__ b1,
                                               const float* __restrict__ W2,
                                               const float* __restrict__ dinv,
                                               const int* __restrict__ rowptr,
                                               const int* __restrict__ csr_src,
                                               const float* __restrict__ csr_nrm,
                                               float* __restrict__ x2w){
  __shared__ float W2s[64*64];
  __shared__ float rows[4][64];
  int lane = threadIdx.x & 63, w = threadIdx.x >> 6;
  for (int o = threadIdx.x; o < 64*64; o += 256) W2s[o] = W2[o];
  __syncthreads();

  int i = blockIdx.x*4 + w;
  float di = dinv[i];
  float acc = di*di * xin[(size_t)i*HD + lane];
  int e = rowptr[i], e1 = rowptr[i+1];
  for (; e + 1 < e1; e += 2){
    int s0 = csr_src[e], s1 = csr_src[e+1];
    float n0 = csr_nrm[e], n1 = csr_nrm[e+1];
    acc += n0 * xin[(size_t)s0*HD + lane];
    acc += n1 * xin[(size_t)s1*HD + lane];
  }
  if (e < e1) acc += csr_nrm[e] * xin[(size_t)csr_src[e]*HD + lane];
  float v = acc + b1[lane];
  rows[w][lane] = v > 0.f ? v : 0.f;
  __syncthreads();

  float acc2 = 0.f;
  #pragma unroll
  for (int k=0;k<64;++k) acc2 += rows[w][k] * W2s[k*64 + lane];
  x2w[(size_t)i*HD + lane] = acc2;
}

// ---------------- agg2 -> bf16 ----------------
__global__ __launch_bounds__(256) void k_agg2(const float* __restrict__ xin,
                                              const float* __restrict__ b2,
                                              const float* __restrict__ dinv,
                                              const int* __restrict__ rowptr,
                                              const int* __restrict__ csr_src,
                                              const float* __restrict__ csr_nrm,
                                              ushort_t* __restrict__ x2b){
  int lane = threadIdx.x & 63, w = threadIdx.x >> 6;
  int i = blockIdx.x*4 + w;
  float di = dinv[i];
  float acc = di*di * xin[(size_t)i*HD + lane];
  int e = rowptr[i], e1 = rowptr[i+1];
  for (; e + 1 < e1; e += 2){
    int s0 = csr_src[e], s1 = csr_src[e+1];
    float n0 = csr_nrm[e], n1 = csr_nrm[e+1];
    acc += n0 * xin[(size_t)s0*HD + lane];
    acc += n1 * xin[(size_t)s1*HD + lane];
  }
  if (e < e1) acc += csr_nrm[e] * xin[(size_t)csr_src[e]*HD + lane];
  float v = acc + b2[lane];
  v = v > 0.f ? v : 0.f;
  x2b[(size_t)i*HD + lane] = bf16_rne(v);
}

// ---------------- FC + softmax, swapped-operand MFMA ----------------
__global__ __launch_bounds__(256) void k_rowsum(const ushort_t* __restrict__ x2b,
                                                const ushort_t* __restrict__ fcwp,
                                                const float* __restrict__ fcb,
                                                float* __restrict__ S){
  int lane = threadIdx.x & 63, w = threadIdx.x >> 6;
  int r = lane & 15, seg = lane >> 4;
  int row0 = blockIdx.x*128 + w*32;
  const ushort_t* xb = x2b + (size_t)(row0 + r)*HD + seg*8;
  v8s x00 = *(const v8s*)(xb);
  v8s x01 = *(const v8s*)(xb + 32);
  v8s x10 = *(const v8s*)(xb + 16*HD);
  v8s x11 = *(const v8s*)(xb + 16*HD + 32);
  float rp0 = 0.f, rp1 = 0.f;
  for (int cb=0; cb<4; ++cb){
    int colbase = blockIdx.y*256 + cb*64;
    f32x4 z = {0.f,0.f,0.f,0.f};
    f32x4 acc0[4] = {z,z,z,z}, acc1[4] = {z,z,z,z};
    #pragma unroll
    for (int nt=0; nt<4; ++nt){
      int cblk = (colbase >> 4) + nt;
      v8s bA = *(const v8s*)(fcwp + ((size_t)cblk*16 + r)*32 + seg*8);
      v8s bB = *(const v8s*)(fcwp + ((size_t)(512 + cblk)*16 + r)*32 + seg*8);
      acc0[nt] = mfma16(bA, x00, acc0[nt]);
      acc0[nt] = mfma16(bB, x01, acc0[nt]);
      acc1[nt] = mfma16(bA, x10, acc1[nt]);
      acc1[nt] = mfma16(bB, x11, acc1[nt]);
    }
    #pragma unroll
    for (int nt=0; nt<4; ++nt){
      int col = colbase + nt*16 + seg*4;
      f32x4 fb = *(const f32x4*)(fcb + col);
      #pragma unroll
      for (int j=0;j<4;++j){
        rp0 += __expf(acc0[nt][j] + fb[j]);
        rp1 += __expf(acc1[nt][j] + fb[j]);
      }
    }
  }
  rp0 += __shfl_xor(rp0, 16); rp0 += __shfl_xor(rp0, 32);
  rp1 += __shfl_xor(rp1, 16); rp1 += __shfl_xor(rp1, 32);
  if (lane < 16){
    atomicAdd(&S[row0 + lane],      rp0);
    atomicAdd(&S[row0 + 16 + lane], rp1);
  }
}

__global__ __launch_bounds__(256) void k_passB(const ushort_t* __restrict__ x2b,
                                               const ushort_t* __restrict__ fcwp,
                                               const float* __restrict__ fcb,
                                               const float* __restrict__ S,
                                               float* __restrict__ out){
  int lane = threadIdx.x & 63, w = threadIdx.x >> 6;
  int r = lane & 15, seg = lane >> 4;
  int row0 = blockIdx.x*128 + w*32;
  const ushort_t* xb = x2b + (size_t)(row0 + r)*HD + seg*8;
  v8s x00 = *(const v8s*)(xb);
  v8s x01 = *(const v8s*)(xb + 32);
  v8s x10 = *(const v8s*)(xb + 16*HD);
  v8s x11 = *(const v8s*)(xb + 16*HD + 32);
  float si0 = 1.0f / S[row0 + r];
  float si1 = 1.0f / S[row0 + 16 + r];
  float* o0 = out + (size_t)(row0 + r)*NN;
  float* o1 = out + (size_t)(row0 + 16 + r)*NN;
  for (int cb=0; cb<4; ++cb){
    int colbase = blockIdx.y*256 + cb*64;
    f32x4 z = {0.f,0.f,0.f,0.f};
    f32x4 acc0[4] = {z,z,z,z}, acc1[4] = {z,z,z,z};
    #pragma unroll
    for (int nt=0; nt<4; ++nt){
      int cblk = (colbase >> 4) + nt;
      v8s bA = *(const v8s*)(fcwp + ((size_t)cblk*16 + r)*32 + seg*8);
      v8s bB = *(const v8s*)(fcwp + ((size_t)(512 + cblk)*16 + r)*32 + seg*8);
      acc0[nt] = mfma16(bA, x00, acc0[nt]);
      acc0[nt] = mfma16(bB, x01, acc0[nt]);
      acc1[nt] = mfma16(bA, x10, acc1[nt]);
      acc1[nt] = mfma16(bB, x11, acc1[nt]);
    }
    #pragma unroll
    for (int nt=0; nt<4; ++nt){
      int col = colbase + nt*16 + seg*4;
      f32x4 fb = *(const f32x4*)(fcb + col);
      f32x4 v0, v1;
      #pragma unroll
      for (int j=0;j<4;++j){
        v0[j] = __expf(acc0[nt][j] + fb[j]) * si0;
        v1[j] = __expf(acc1[nt][j] + fb[j]) * si1;
      }
      *(f32x4*)(o0 + col) = v0;
      *(f32x4*)(o1 + col) = v1;
    }
  }
}

// ---------------- host ----------------
extern "C" void kernel_launch(void* const* d_in, const int* in_sizes, int n_in,
                              void* d_out, int out_size, void* d_ws, size_t ws_size,
                              hipStream_t stream){
  (void)in_sizes; (void)n_in; (void)out_size; (void)ws_size;
  const int*   ei  = (const int*)  d_in[0];
  const float* ew  = (const float*)d_in[1];
  const float* X   = (const float*)d_in[2];
  const float* W1  = (const float*)d_in[3];
  const float* b1  = (const float*)d_in[4];
  const float* W2  = (const float*)d_in[5];
  const float* b2  = (const float*)d_in[6];
  const float* fcW = (const float*)d_in[7];
  const float* fcb = (const float*)d_in[8];
  float* out = (float*)d_out;
  char*  ws  = (char*)d_ws;

  float*    deg     = (float*)   (ws + 0);
  float*    dinv    = (float*)   (ws + 32768);
  int*      cnt     = (int*)     (ws + 65536);
  int*      wcnt    = (int*)     (ws + 98304);
  int*      rowptr  = (int*)     (ws + 131072);
  int*      csr_src = (int*)     (ws + 167936);
  float*    csr_nrm = (float*)   (ws + 1216512);
  ushort_t* w1hi    = (ushort_t*)(ws + 2265088);
  ushort_t* w1lo    = (ushort_t*)(ws + 3313664);
  ushort_t* fcwp    = (ushort_t*)(ws + 4362240);
  float*    xw1p    = (float*)   (ws + 5410816);   // NKC * 2 MB = 16 MB
  float*    xw1     = (float*)   (ws + 22188032);
  float*    x2w     = (float*)   (ws + 24285184);
  ushort_t* x2b     = (ushort_t*)(ws + 26382336);
  float*    S       = (float*)   (ws + 27430912);

  k_prep0   <<<2048, 256, 0, stream>>>(W1, fcW, w1hi, w1lo, fcwp, deg, cnt, wcnt, S);
  k_deg_cnt <<<1024, 256, 0, stream>>>(ei, ew, deg, cnt);
  k_scan    <<<1,    256, 0, stream>>>(cnt, deg, rowptr, dinv);
  k_fill    <<<1024, 256, 0, stream>>>(ei, ew, dinv, rowptr, wcnt, csr_src, csr_nrm);
  k_gemm1   <<<dim3(128, NKC), 256, 0, stream>>>(X, w1hi, w1lo, xw1p);
  k_red     <<<512,  256, 0, stream>>>(xw1p, xw1);
  k_agg1c   <<<2048, 256, 0, stream>>>(xw1, b1, W2, dinv, rowptr, csr_src, csr_nrm, x2w);
  k_agg2    <<<2048, 256, 0, stream>>>(x2w, b2, dinv, rowptr, csr_src, csr_nrm, x2b);
  k_rowsum  <<<dim3(64,32), 256, 0, stream>>>(x2b, fcwp, fcb, S);
  k_passB   <<<dim3(64,32), 256, 0, stream>>>(x2b, fcwp, fcb, S, out);
}

// Round 4
// 302.641 us; speedup vs baseline: 1.0599x; 1.0599x over previous
//
#include <hip/hip_runtime.h>

// TSP_GNN: 2x GCNConv(edge-weighted, self-loops) + FC + row softmax.
// N=8192 nodes, E=262144 edges, H=64.
// R4: gemm1 = explicit 2-slot software pipeline (loads for it+2 issued behind
// consumption of it -> counted vmcnt, no per-iter drain), 32 rows/wave,
// trunc-based hi/lo split. Rest unchanged from R3.

#define NN 8192
#define NE 262144
#define HD 64
#define KCH 1024   // K-chunk per gemm1 block
#define NKC 8      // number of K-chunks

typedef float f32x4 __attribute__((ext_vector_type(4)));
typedef short v8s   __attribute__((ext_vector_type(8)));
typedef unsigned short ushort_t;

__device__ __forceinline__ unsigned short bf16_rne(float f){
  union { float f; unsigned u; } v; v.f = f;
  unsigned r = v.u + 0x7fffu + ((v.u >> 16) & 1u);
  return (unsigned short)(r >> 16);
}
__device__ __forceinline__ float bf16_f32(unsigned short h){
  union { unsigned u; float f; } v; v.u = ((unsigned)h) << 16;
  return v.f;
}
__device__ __forceinline__ f32x4 mfma16(v8s a, v8s b, f32x4 c){
  return __builtin_amdgcn_mfma_f32_16x16x32_bf16(a, b, c, 0, 0, 0);
}

// truncation split: hi = top16(f), lo = bf16(f - hi). Error ~2^-16 rel (same
// scale as the dropped al*bl term); ~5 VALU/elem vs ~10 for double-RNE.
__device__ __forceinline__ void split_tr(float f, short& hi, short& lo){
  unsigned u = __float_as_uint(f);
  hi = (short)(u >> 16);
  float fh = __uint_as_float(u & 0xffff0000u);
  float d = f - fh;
  lo = (short)(__float_as_uint(d) >> 16);
}

// ---------------- prep: init + pack W1 (hi/lo) + pack fcW ----------------
// W1 [8192][64]: idx = ((kb*4+nt)*16+c)*32+kk  (k=kb*32+kk, col=nt*16+c)
// fcW [64][8192]: idx = ((kb*512+cblk)*16+c)*32+kk (k=kb*32+kk, col=cblk*16+c)
__global__ void k_prep0(const float* __restrict__ W1, const float* __restrict__ fcW,
                        ushort_t* w1hi, ushort_t* w1lo, ushort_t* fcwp,
                        float* deg, int* cnt, int* wcnt, float* S){
  int idx = blockIdx.x*blockDim.x + threadIdx.x;   // 0..524287
  if (idx < NN){ deg[idx]=1.0f; cnt[idx]=0; wcnt[idx]=0; S[idx]=0.0f; }
  {
    int kk = idx & 31, c = (idx>>5)&15, nt = (idx>>9)&3, kb = idx>>11;
    int k = kb*32 + kk, col = nt*16 + c;
    float w = W1[(size_t)k*HD + col];
    unsigned short hi = bf16_rne(w);
    w1hi[idx] = hi;
    w1lo[idx] = bf16_rne(w - bf16_f32(hi));
  }
  {
    int kk = idx & 31, c = (idx>>5)&15, cblk = (idx>>9)&511, kb = idx>>18;
    int k = kb*32 + kk, col = cblk*16 + c;
    fcwp[idx] = bf16_rne(fcW[(size_t)k*NN + col]);
  }
}

__global__ void k_deg_cnt(const int* ei, const float* ew, float* deg, int* cnt){
  int e = blockIdx.x*blockDim.x + threadIdx.x;
  if (e < NE){
    int d = ei[NE + e];                 // dst
    atomicAdd(&deg[d], ew[e]);
    atomicAdd(&cnt[d], 1);
  }
}

// single-block: exclusive scan of counts -> rowptr, plus dinv = 1/sqrt(deg)
__global__ void k_scan(const int* cnt, const float* deg, int* rowptr, float* dinv){
  __shared__ int part[256];
  int t = threadIdx.x;
  int loc[32]; int s = 0;
  #pragma unroll
  for (int j=0;j<32;++j){ loc[j] = cnt[t*32+j]; s += loc[j]; }
  part[t] = s; __syncthreads();
  for (int off=1; off<256; off<<=1){
    int v = (t >= off) ? part[t-off] : 0;
    __syncthreads();
    part[t] += v;
    __syncthreads();
  }
  int run = part[t] - s;
  #pragma unroll
  for (int j=0;j<32;++j){ rowptr[t*32+j] = run; run += loc[j]; }
  if (t == 255) rowptr[NN] = run;
  #pragma unroll
  for (int j=0;j<32;++j) dinv[t*32+j] = 1.0f / sqrtf(deg[t*32+j]);
}

__global__ void k_fill(const int* ei, const float* ew, const float* dinv,
                       const int* rowptr, int* wcnt, int* csr_src, float* csr_nrm){
  int e = blockIdx.x*blockDim.x + threadIdx.x;
  if (e < NE){
    int s = ei[e], d = ei[NE+e];
    int slot = rowptr[d] + atomicAdd(&wcnt[d], 1);
    csr_src[slot] = s;
    csr_nrm[slot] = dinv[s] * ew[e] * dinv[d];
  }
}

// ---------------- GEMM1: xw1p[kc] = X[:, kc] @ W1[kc, :] ----------------
// block = 256 thr (4 waves), wave owns 32 rows (2 MFMA tiles) x KCH.
// 2-slot pipeline: loads for it+2 issued after consumption of it.
// grid = (64 row-tiles, NKC k-chunks) = 512 blocks -> 2 blocks/CU.
__global__ __launch_bounds__(256, 2) void k_gemm1(const float* __restrict__ X,
                                                  const ushort_t* __restrict__ w1hi,
                                                  const ushort_t* __restrict__ w1lo,
                                                  float* __restrict__ xw1p){
  int lane = threadIdx.x & 63, w = threadIdx.x >> 6;
  int r = lane & 15, seg = lane >> 4;
  int row0 = blockIdx.x*128 + w*32;
  int kb0 = blockIdx.y * KCH;
  const float* xr0 = X + (size_t)(row0 + r)      * NN + kb0 + seg*8;
  const float* xr1 = X + (size_t)(row0 + 16 + r) * NN + kb0 + seg*8;
  // B fragment bases: off(it,nt) = it*2048 + nt*512 (elements)
  const ushort_t* bhp = w1hi + (size_t)(kb0 >> 5)*2048 + r*32 + seg*8;
  const ushort_t* blp = w1lo + (size_t)(kb0 >> 5)*2048 + r*32 + seg*8;

  f32x4 z = {0.f,0.f,0.f,0.f};
  f32x4 acc0[4] = {z,z,z,z};
  f32x4 acc1[4] = {z,z,z,z};

  // pipeline slots
  f32x4 A00_0, A01_0, A10_0, A11_0;   // slot 0: even iterations
  f32x4 A00_1, A01_1, A10_1, A11_1;   // slot 1: odd iterations
  v8s bh0[4], bl0[4], bh1[4], bl1[4];

  // prologue: it=0 -> slot0, it=1 -> slot1
  A00_0 = *(const f32x4*)(xr0);        A01_0 = *(const f32x4*)(xr0 + 4);
  A10_0 = *(const f32x4*)(xr1);        A11_0 = *(const f32x4*)(xr1 + 4);
  A00_1 = *(const f32x4*)(xr0 + 32);   A01_1 = *(const f32x4*)(xr0 + 36);
  A10_1 = *(const f32x4*)(xr1 + 32);   A11_1 = *(const f32x4*)(xr1 + 36);
  #pragma unroll
  for (int nt=0; nt<4; ++nt){
    bh0[nt] = *(const v8s*)(bhp + nt*512);
    bl0[nt] = *(const v8s*)(blp + nt*512);
    bh1[nt] = *(const v8s*)(bhp + 2048 + nt*512);
    bl1[nt] = *(const v8s*)(blp + 2048 + nt*512);
  }

  auto body = [&](int it, f32x4& A00, f32x4& A01, f32x4& A10, f32x4& A11,
                  v8s (&bh)[4], v8s (&bl)[4]){
    // 1) convert current A (frees the A regs)
    v8s ah0, al0, ah1, al1;
    #pragma unroll
    for (int j=0;j<4;++j){
      short h,l;
      split_tr(A00[j], h, l); ah0[j]   = h; al0[j]   = l;
      split_tr(A01[j], h, l); ah0[4+j] = h; al0[4+j] = l;
      split_tr(A10[j], h, l); ah1[j]   = h; al1[j]   = l;
      split_tr(A11[j], h, l); ah1[4+j] = h; al1[4+j] = l;
    }
    int itn = (it + 2) & 31;           // tail wraps: harmless reload
    // 2) reload A slot for it+2
    A00 = *(const f32x4*)(xr0 + itn*32);  A01 = *(const f32x4*)(xr0 + itn*32 + 4);
    A10 = *(const f32x4*)(xr1 + itn*32);  A11 = *(const f32x4*)(xr1 + itn*32 + 4);
    // 3) MFMAs (consume B slot)
    #pragma unroll
    for (int nt=0; nt<4; ++nt){
      acc0[nt] = mfma16(ah0, bh[nt], acc0[nt]);
      acc0[nt] = mfma16(ah0, bl[nt], acc0[nt]);
      acc0[nt] = mfma16(al0, bh[nt], acc0[nt]);
      acc1[nt] = mfma16(ah1, bh[nt], acc1[nt]);
      acc1[nt] = mfma16(ah1, bl[nt], acc1[nt]);
      acc1[nt] = mfma16(al1, bh[nt], acc1[nt]);
    }
    // 4) reload B slot for it+2
    #pragma unroll
    for (int nt=0; nt<4; ++nt){
      bh[nt] = *(const v8s*)(bhp + (size_t)itn*2048 + nt*512);
      bl[nt] = *(const v8s*)(blp + (size_t)itn*2048 + nt*512);
    }
  };

  for (int j = 0; j < 16; ++j){
    body(2*j,     A00_0, A01_0, A10_0, A11_0, bh0, bl0);
    body(2*j + 1, A00_1, A01_1, A10_1, A11_1, bh1, bl1);
  }

  // D layout per tile: row-within-16 = 4*seg+j, col = nt*16+r
  float* o = xw1p + (size_t)blockIdx.y*(NN*HD) + (size_t)row0*HD;
  #pragma unroll
  for (int nt=0; nt<4; ++nt)
    #pragma unroll
    for (int j=0;j<4;++j){
      o[(4*seg + j)*HD + nt*16 + r]        = acc0[nt][j];
      o[(16 + 4*seg + j)*HD + nt*16 + r]   = acc1[nt][j];
    }
}

// reduce NKC partial planes -> xw1
__global__ __launch_bounds__(256) void k_red(const float* __restrict__ xw1p,
                                             float* __restrict__ xw1){
  int i = blockIdx.x*blockDim.x + threadIdx.x;   // over NN*HD/4
  f32x4 s = {0.f,0.f,0.f,0.f};
  #pragma unroll
  for (int c=0;c<NKC;++c){
    f32x4 v = *(const f32x4*)(xw1p + (size_t)c*NN*HD + (size_t)i*4);
    s[0]+=v[0]; s[1]+=v[1]; s[2]+=v[2]; s[3]+=v[3];
  }
  *(f32x4*)(xw1 + (size_t)i*4) = s;
}

// ---------------- agg1 + conv2 fused ----------------
__global__ __launch_bounds__(256) void k_agg1c(const float* __restrict__ xin,
                                               const float* __restrict__ b1,
                                               const float* __restrict__ W2,
                                               const float* __restrict__ dinv,
                                               const int* __restrict__ rowptr,
                                               const int* __restrict__ csr_src,
                                               const float* __restrict__ csr_nrm,
                                               float* __restrict__ x2w){
  __shared__ float W2s[64*64];
  __shared__ float rows[4][64];
  int lane = threadIdx.x & 63, w = threadIdx.x >> 6;
  for (int o = threadIdx.x; o < 64*64; o += 256) W2s[o] = W2[o];
  __syncthreads();

  int i = blockIdx.x*4 + w;
  float di = dinv[i];
  float acc = di*di * xin[(size_t)i*HD + lane];
  int e = rowptr[i], e1 = rowptr[i+1];
  for (; e + 1 < e1; e += 2){
    int s0 = csr_src[e], s1 = csr_src[e+1];
    float n0 = csr_nrm[e], n1 = csr_nrm[e+1];
    acc += n0 * xin[(size_t)s0*HD + lane];
    acc += n1 * xin[(size_t)s1*HD + lane];
  }
  if (e < e1) acc += csr_nrm[e] * xin[(size_t)csr_src[e]*HD + lane];
  float v = acc + b1[lane];
  rows[w][lane] = v > 0.f ? v : 0.f;
  __syncthreads();

  float acc2 = 0.f;
  #pragma unroll
  for (int k=0;k<64;++k) acc2 += rows[w][k] * W2s[k*64 + lane];
  x2w[(size_t)i*HD + lane] = acc2;
}

// ---------------- agg2 -> bf16 ----------------
__global__ __launch_bounds__(256) void k_agg2(const float* __restrict__ xin,
                                              const float* __restrict__ b2,
                                              const float* __restrict__ dinv,
                                              const int* __restrict__ rowptr,
                                              const int* __restrict__ csr_src,
                                              const float* __restrict__ csr_nrm,
                                              ushort_t* __restrict__ x2b){
  int lane = threadIdx.x & 63, w = threadIdx.x >> 6;
  int i = blockIdx.x*4 + w;
  float di = dinv[i];
  float acc = di*di * xin[(size_t)i*HD + lane];
  int e = rowptr[i], e1 = rowptr[i+1];
  for (; e + 1 < e1; e += 2){
    int s0 = csr_src[e], s1 = csr_src[e+1];
    float n0 = csr_nrm[e], n1 = csr_nrm[e+1];
    acc += n0 * xin[(size_t)s0*HD + lane];
    acc += n1 * xin[(size_t)s1*HD + lane];
  }
  if (e < e1) acc += csr_nrm[e] * xin[(size_t)csr_src[e]*HD + lane];
  float v = acc + b2[lane];
  v = v > 0.f ? v : 0.f;
  x2b[(size_t)i*HD + lane] = bf16_rne(v);
}

// ---------------- FC + softmax, swapped-operand MFMA ----------------
__global__ __launch_bounds__(256) void k_rowsum(const ushort_t* __restrict__ x2b,
                                                const ushort_t* __restrict__ fcwp,
                                                const float* __restrict__ fcb,
                                                float* __restrict__ S){
  int lane = threadIdx.x & 63, w = threadIdx.x >> 6;
  int r = lane & 15, seg = lane >> 4;
  int row0 = blockIdx.x*128 + w*32;
  const ushort_t* xb = x2b + (size_t)(row0 + r)*HD + seg*8;
  v8s x00 = *(const v8s*)(xb);
  v8s x01 = *(const v8s*)(xb + 32);
  v8s x10 = *(const v8s*)(xb + 16*HD);
  v8s x11 = *(const v8s*)(xb + 16*HD + 32);
  float rp0 = 0.f, rp1 = 0.f;
  for (int cb=0; cb<4; ++cb){
    int colbase = blockIdx.y*256 + cb*64;
    f32x4 z = {0.f,0.f,0.f,0.f};
    f32x4 acc0[4] = {z,z,z,z}, acc1[4] = {z,z,z,z};
    #pragma unroll
    for (int nt=0; nt<4; ++nt){
      int cblk = (colbase >> 4) + nt;
      v8s bA = *(const v8s*)(fcwp + ((size_t)cblk*16 + r)*32 + seg*8);
      v8s bB = *(const v8s*)(fcwp + ((size_t)(512 + cblk)*16 + r)*32 + seg*8);
      acc0[nt] = mfma16(bA, x00, acc0[nt]);
      acc0[nt] = mfma16(bB, x01, acc0[nt]);
      acc1[nt] = mfma16(bA, x10, acc1[nt]);
      acc1[nt] = mfma16(bB, x11, acc1[nt]);
    }
    #pragma unroll
    for (int nt=0; nt<4; ++nt){
      int col = colbase + nt*16 + seg*4;
      f32x4 fb = *(const f32x4*)(fcb + col);
      #pragma unroll
      for (int j=0;j<4;++j){
        rp0 += __expf(acc0[nt][j] + fb[j]);
        rp1 += __expf(acc1[nt][j] + fb[j]);
      }
    }
  }
  rp0 += __shfl_xor(rp0, 16); rp0 += __shfl_xor(rp0, 32);
  rp1 += __shfl_xor(rp1, 16); rp1 += __shfl_xor(rp1, 32);
  if (lane < 16){
    atomicAdd(&S[row0 + lane],      rp0);
    atomicAdd(&S[row0 + 16 + lane], rp1);
  }
}

__global__ __launch_bounds__(256) void k_passB(const ushort_t* __restrict__ x2b,
                                               const ushort_t* __restrict__ fcwp,
                                               const float* __restrict__ fcb,
                                               const float* __restrict__ S,
                                               float* __restrict__ out){
  int lane = threadIdx.x & 63, w = threadIdx.x >> 6;
  int r = lane & 15, seg = lane >> 4;
  int row0 = blockIdx.x*128 + w*32;
  const ushort_t* xb = x2b + (size_t)(row0 + r)*HD + seg*8;
  v8s x00 = *(const v8s*)(xb);
  v8s x01 = *(const v8s*)(xb + 32);
  v8s x10 = *(const v8s*)(xb + 16*HD);
  v8s x11 = *(const v8s*)(xb + 16*HD + 32);
  float si0 = 1.0f / S[row0 + r];
  float si1 = 1.0f / S[row0 + 16 + r];
  float* o0 = out + (size_t)(row0 + r)*NN;
  float* o1 = out + (size_t)(row0 + 16 + r)*NN;
  for (int cb=0; cb<4; ++cb){
    int colbase = blockIdx.y*256 + cb*64;
    f32x4 z = {0.f,0.f,0.f,0.f};
    f32x4 acc0[4] = {z,z,z,z}, acc1[4] = {z,z,z,z};
    #pragma unroll
    for (int nt=0; nt<4; ++nt){
      int cblk = (colbase >> 4) + nt;
      v8s bA = *(const v8s*)(fcwp + ((size_t)cblk*16 + r)*32 + seg*8);
      v8s bB = *(const v8s*)(fcwp + ((size_t)(512 + cblk)*16 + r)*32 + seg*8);
      acc0[nt] = mfma16(bA, x00, acc0[nt]);
      acc0[nt] = mfma16(bB, x01, acc0[nt]);
      acc1[nt] = mfma16(bA, x10, acc1[nt]);
      acc1[nt] = mfma16(bB, x11, acc1[nt]);
    }
    #pragma unroll
    for (int nt=0; nt<4; ++nt){
      int col = colbase + nt*16 + seg*4;
      f32x4 fb = *(const f32x4*)(fcb + col);
      f32x4 v0, v1;
      #pragma unroll
      for (int j=0;j<4;++j){
        v0[j] = __expf(acc0[nt][j] + fb[j]) * si0;
        v1[j] = __expf(acc1[nt][j] + fb[j]) * si1;
      }
      *(f32x4*)(o0 + col) = v0;
      *(f32x4*)(o1 + col) = v1;
    }
  }
}

// ---------------- host ----------------
extern "C" void kernel_launch(void* const* d_in, const int* in_sizes, int n_in,
                              void* d_out, int out_size, void* d_ws, size_t ws_size,
                              hipStream_t stream){
  (void)in_sizes; (void)n_in; (void)out_size; (void)ws_size;
  const int*   ei  = (const int*)  d_in[0];
  const float* ew  = (const float*)d_in[1];
  const float* X   = (const float*)d_in[2];
  const float* W1  = (const float*)d_in[3];
  const float* b1  = (const float*)d_in[4];
  const float* W2  = (const float*)d_in[5];
  const float* b2  = (const float*)d_in[6];
  const float* fcW = (const float*)d_in[7];
  const float* fcb = (const float*)d_in[8];
  float* out = (float*)d_out;
  char*  ws  = (char*)d_ws;

  float*    deg     = (float*)   (ws + 0);
  float*    dinv    = (float*)   (ws + 32768);
  int*      cnt     = (int*)     (ws + 65536);
  int*      wcnt    = (int*)     (ws + 98304);
  int*      rowptr  = (int*)     (ws + 131072);
  int*      csr_src = (int*)     (ws + 167936);
  float*    csr_nrm = (float*)   (ws + 1216512);
  ushort_t* w1hi    = (ushort_t*)(ws + 2265088);
  ushort_t* w1lo    = (ushort_t*)(ws + 3313664);
  ushort_t* fcwp    = (ushort_t*)(ws + 4362240);
  float*    xw1p    = (float*)   (ws + 5410816);   // NKC * 2 MB = 16 MB
  float*    xw1     = (float*)   (ws + 22188032);
  float*    x2w     = (float*)   (ws + 24285184);
  ushort_t* x2b     = (ushort_t*)(ws + 26382336);
  float*    S       = (float*)   (ws + 27430912);

  k_prep0   <<<2048, 256, 0, stream>>>(W1, fcW, w1hi, w1lo, fcwp, deg, cnt, wcnt, S);
  k_deg_cnt <<<1024, 256, 0, stream>>>(ei, ew, deg, cnt);
  k_scan    <<<1,    256, 0, stream>>>(cnt, deg, rowptr, dinv);
  k_fill    <<<1024, 256, 0, stream>>>(ei, ew, dinv, rowptr, wcnt, csr_src, csr_nrm);
  k_gemm1   <<<dim3(64, NKC), 256, 0, stream>>>(X, w1hi, w1lo, xw1p);
  k_red     <<<512,  256, 0, stream>>>(xw1p, xw1);
  k_agg1c   <<<2048, 256, 0, stream>>>(xw1, b1, W2, dinv, rowptr, csr_src, csr_nrm, x2w);
  k_agg2    <<<2048, 256, 0, stream>>>(x2w, b2, dinv, rowptr, csr_src, csr_nrm, x2b);
  k_rowsum  <<<dim3(64,32), 256, 0, stream>>>(x2b, fcwp, fcb, S);
  k_passB   <<<dim3(64,32), 256, 0, stream>>>(x2b, fcwp, fcb, S, out);
}

// Round 5
// 293.397 us; speedup vs baseline: 1.0933x; 1.0315x over previous
//
#include <hip/hip_runtime.h>

// TSP_GNN: 2x GCNConv(edge-weighted, self-loops) + FC + row softmax.
// N=8192 nodes, E=262144 edges, H=64.
// R5: gemm1 = m97-style global_load_lds double-buffered A staging (fp32 tile,
// XOR-swizzled source + swizzled ds_read), convert in-reg, B global->reg.
// Block = 2 waves x 32 rows = 64 rows x KCH=1024; grid (128,8) = 4 blocks/CU.

#define NN 8192
#define NE 262144
#define HD 64
#define KCH 1024   // K-chunk per gemm1 block
#define NKC 8      // number of K-chunks

typedef float f32x4 __attribute__((ext_vector_type(4)));
typedef short v8s   __attribute__((ext_vector_type(8)));
typedef unsigned short ushort_t;

__device__ __forceinline__ unsigned short bf16_rne(float f){
  union { float f; unsigned u; } v; v.f = f;
  unsigned r = v.u + 0x7fffu + ((v.u >> 16) & 1u);
  return (unsigned short)(r >> 16);
}
__device__ __forceinline__ float bf16_f32(unsigned short h){
  union { unsigned u; float f; } v; v.u = ((unsigned)h) << 16;
  return v.f;
}
__device__ __forceinline__ f32x4 mfma16(v8s a, v8s b, f32x4 c){
  return __builtin_amdgcn_mfma_f32_16x16x32_bf16(a, b, c, 0, 0, 0);
}
// truncation split: hi = top16(f), lo = bf16(f - hi).
__device__ __forceinline__ void split_tr(float f, short& hi, short& lo){
  unsigned u = __float_as_uint(f);
  hi = (short)(u >> 16);
  float fh = __uint_as_float(u & 0xffff0000u);
  float d = f - fh;
  lo = (short)(__float_as_uint(d) >> 16);
}
// async global->LDS, 16B per lane; lds base must be wave-uniform.
__device__ __forceinline__ void gload16(const void* g, void* l){
  __builtin_amdgcn_global_load_lds(
      (const __attribute__((address_space(1))) unsigned int*)g,
      (__attribute__((address_space(3))) unsigned int*)l, 16, 0, 0);
}

// ---------------- prep: init + pack W1 (hi/lo) + pack fcW ----------------
__global__ void k_prep0(const float* __restrict__ W1, const float* __restrict__ fcW,
                        ushort_t* w1hi, ushort_t* w1lo, ushort_t* fcwp,
                        float* deg, int* cnt, int* wcnt, float* S){
  int idx = blockIdx.x*blockDim.x + threadIdx.x;   // 0..524287
  if (idx < NN){ deg[idx]=1.0f; cnt[idx]=0; wcnt[idx]=0; S[idx]=0.0f; }
  {
    int kk = idx & 31, c = (idx>>5)&15, nt = (idx>>9)&3, kb = idx>>11;
    int k = kb*32 + kk, col = nt*16 + c;
    float w = W1[(size_t)k*HD + col];
    unsigned short hi = bf16_rne(w);
    w1hi[idx] = hi;
    w1lo[idx] = bf16_rne(w - bf16_f32(hi));
  }
  {
    int kk = idx & 31, c = (idx>>5)&15, cblk = (idx>>9)&511, kb = idx>>18;
    int k = kb*32 + kk, col = cblk*16 + c;
    fcwp[idx] = bf16_rne(fcW[(size_t)k*NN + col]);
  }
}

__global__ void k_deg_cnt(const int* ei, const float* ew, float* deg, int* cnt){
  int e = blockIdx.x*blockDim.x + threadIdx.x;
  if (e < NE){
    int d = ei[NE + e];
    atomicAdd(&deg[d], ew[e]);
    atomicAdd(&cnt[d], 1);
  }
}

__global__ void k_scan(const int* cnt, const float* deg, int* rowptr, float* dinv){
  __shared__ int part[256];
  int t = threadIdx.x;
  int loc[32]; int s = 0;
  #pragma unroll
  for (int j=0;j<32;++j){ loc[j] = cnt[t*32+j]; s += loc[j]; }
  part[t] = s; __syncthreads();
  for (int off=1; off<256; off<<=1){
    int v = (t >= off) ? part[t-off] : 0;
    __syncthreads();
    part[t] += v;
    __syncthreads();
  }
  int run = part[t] - s;
  #pragma unroll
  for (int j=0;j<32;++j){ rowptr[t*32+j] = run; run += loc[j]; }
  if (t == 255) rowptr[NN] = run;
  #pragma unroll
  for (int j=0;j<32;++j) dinv[t*32+j] = 1.0f / sqrtf(deg[t*32+j]);
}

__global__ void k_fill(const int* ei, const float* ew, const float* dinv,
                       const int* rowptr, int* wcnt, int* csr_src, float* csr_nrm){
  int e = blockIdx.x*blockDim.x + threadIdx.x;
  if (e < NE){
    int s = ei[e], d = ei[NE+e];
    int slot = rowptr[d] + atomicAdd(&wcnt[d], 1);
    csr_src[slot] = s;
    csr_nrm[slot] = dinv[s] * ew[e] * dinv[d];
  }
}

// ---------------- GEMM1: xw1p[kc] = X[:, kc] @ W1[kc, :] ----------------
// 2 waves x 32 rows; A staged fp32 in LDS (dbuf, swizzled); B global->reg.
__global__ __launch_bounds__(128, 2) void k_gemm1(const float* __restrict__ X,
                                                  const ushort_t* __restrict__ w1hi,
                                                  const ushort_t* __restrict__ w1lo,
                                                  float* __restrict__ xw1p){
  __shared__ char bufA[2][64*128];   // 2 x 8KB: [row 0..63][32 fp32], 16B-swizzled
  int lane = threadIdx.x & 63, w = threadIdx.x >> 6;
  int r = lane & 15, seg = lane >> 4;
  int row0 = blockIdx.x*64;
  int kb0 = blockIdx.y * KCH;

  // staging source: lane covers row (lane>>3) of each 8-row group, 16B seg (lane&7),
  // column-swizzled by row so LDS content is byte-XOR-swizzled.
  int srow = lane >> 3;                    // 0..7 within group
  int scolb = ((lane & 7)*16) ^ ((srow & 7) << 4);
  const char* g0 = (const char*)(X + (size_t)(row0 + w*32 + srow)*NN + kb0) + scolb;
  const size_t gRow8 = (size_t)8*NN*4;     // 8 rows stride
  // LDS dest bases (wave-uniform): wave w stages rows w*32 .. w*32+31 (4 instrs)
  // B fragment base
  const ushort_t* bhp = w1hi + (size_t)(kb0 >> 5)*2048 + r*32 + seg*8;
  const ushort_t* blp = w1lo + (size_t)(kb0 >> 5)*2048 + r*32 + seg*8;

  f32x4 z = {0.f,0.f,0.f,0.f};
  f32x4 acc0[4] = {z,z,z,z};
  f32x4 acc1[4] = {z,z,z,z};

  // ds_read addresses (byte, swizzled): rows w*32+r and w*32+16+r
  int swz = (r & 7) << 4;
  int a0b = (w*32 + r)*128;
  int a1b = (w*32 + 16 + r)*128;
  int c0 = (seg*32) ^ swz;          // first 16B of the 8-float group
  int c1 = (seg*32 + 16) ^ swz;     // second 16B

  // prologue: stage step 0 into buf0
  #pragma unroll
  for (int i=0;i<4;++i)
    gload16(g0 + i*gRow8, &bufA[0][(w*32 + i*8)*128]);

  const int NT = KCH/32;   // 32 steps
  for (int t = 0; t < NT; ++t){
    __syncthreads();       // drains stage(t); protects buf[(t+1)&1] from step t-1 readers
    int cur = t & 1;
    if (t + 1 < NT){
      #pragma unroll
      for (int i=0;i<4;++i)
        gload16(g0 + i*gRow8 + (size_t)(t+1)*128, &bufA[cur^1][(w*32 + i*8)*128]);
    }
    // B regs for step t (L2-hot)
    v8s bh[4], bl[4];
    #pragma unroll
    for (int nt=0; nt<4; ++nt){
      bh[nt] = *(const v8s*)(bhp + (size_t)t*2048 + nt*512);
      bl[nt] = *(const v8s*)(blp + (size_t)t*2048 + nt*512);
    }
    // A fragments from LDS (swizzled)
    const char* base = bufA[cur];
    f32x4 A00 = *(const f32x4*)(base + a0b + c0);
    f32x4 A01 = *(const f32x4*)(base + a0b + c1);
    f32x4 A10 = *(const f32x4*)(base + a1b + c0);
    f32x4 A11 = *(const f32x4*)(base + a1b + c1);
    v8s ah0, al0, ah1, al1;
    #pragma unroll
    for (int j=0;j<4;++j){
      short h,l;
      split_tr(A00[j], h, l); ah0[j]   = h; al0[j]   = l;
      split_tr(A01[j], h, l); ah0[4+j] = h; al0[4+j] = l;
      split_tr(A10[j], h, l); ah1[j]   = h; al1[j]   = l;
      split_tr(A11[j], h, l); ah1[4+j] = h; al1[4+j] = l;
    }
    #pragma unroll
    for (int nt=0; nt<4; ++nt){
      acc0[nt] = mfma16(ah0, bh[nt], acc0[nt]);
      acc0[nt] = mfma16(ah0, bl[nt], acc0[nt]);
      acc0[nt] = mfma16(al0, bh[nt], acc0[nt]);
      acc1[nt] = mfma16(ah1, bh[nt], acc1[nt]);
      acc1[nt] = mfma16(ah1, bl[nt], acc1[nt]);
      acc1[nt] = mfma16(al1, bh[nt], acc1[nt]);
    }
  }

  // D layout per tile: row-within-16 = 4*seg+j, col = nt*16+r
  float* o = xw1p + (size_t)blockIdx.y*(NN*HD) + (size_t)(row0 + w*32)*HD;
  #pragma unroll
  for (int nt=0; nt<4; ++nt)
    #pragma unroll
    for (int j=0;j<4;++j){
      o[(4*seg + j)*HD + nt*16 + r]        = acc0[nt][j];
      o[(16 + 4*seg + j)*HD + nt*16 + r]   = acc1[nt][j];
    }
}

// reduce NKC partial planes -> xw1
__global__ __launch_bounds__(256) void k_red(const float* __restrict__ xw1p,
                                             float* __restrict__ xw1){
  int i = blockIdx.x*blockDim.x + threadIdx.x;   // over NN*HD/4
  f32x4 s = {0.f,0.f,0.f,0.f};
  #pragma unroll
  for (int c=0;c<NKC;++c){
    f32x4 v = *(const f32x4*)(xw1p + (size_t)c*NN*HD + (size_t)i*4);
    s[0]+=v[0]; s[1]+=v[1]; s[2]+=v[2]; s[3]+=v[3];
  }
  *(f32x4*)(xw1 + (size_t)i*4) = s;
}

// ---------------- agg1 + conv2 fused ----------------
__global__ __launch_bounds__(256) void k_agg1c(const float* __restrict__ xin,
                                               const float* __restrict__ b1,
                                               const float* __restrict__ W2,
                                               const float* __restrict__ dinv,
                                               const int* __restrict__ rowptr,
                                               const int* __restrict__ csr_src,
                                               const float* __restrict__ csr_nrm,
                                               float* __restrict__ x2w){
  __shared__ float W2s[64*64];
  __shared__ float rows[4][64];
  int lane = threadIdx.x & 63, w = threadIdx.x >> 6;
  for (int o = threadIdx.x; o < 64*64; o += 256) W2s[o] = W2[o];
  __syncthreads();

  int i = blockIdx.x*4 + w;
  float di = dinv[i];
  float acc = di*di * xin[(size_t)i*HD + lane];
  int e = rowptr[i], e1 = rowptr[i+1];
  for (; e + 1 < e1; e += 2){
    int s0 = csr_src[e], s1 = csr_src[e+1];
    float n0 = csr_nrm[e], n1 = csr_nrm[e+1];
    acc += n0 * xin[(size_t)s0*HD + lane];
    acc += n1 * xin[(size_t)s1*HD + lane];
  }
  if (e < e1) acc += csr_nrm[e] * xin[(size_t)csr_src[e]*HD + lane];
  float v = acc + b1[lane];
  rows[w][lane] = v > 0.f ? v : 0.f;
  __syncthreads();

  float acc2 = 0.f;
  #pragma unroll
  for (int k=0;k<64;++k) acc2 += rows[w][k] * W2s[k*64 + lane];
  x2w[(size_t)i*HD + lane] = acc2;
}

// ---------------- agg2 -> bf16 ----------------
__global__ __launch_bounds__(256) void k_agg2(const float* __restrict__ xin,
                                              const float* __restrict__ b2,
                                              const float* __restrict__ dinv,
                                              const int* __restrict__ rowptr,
                                              const int* __restrict__ csr_src,
                                              const float* __restrict__ csr_nrm,
                                              ushort_t* __restrict__ x2b){
  int lane = threadIdx.x & 63, w = threadIdx.x >> 6;
  int i = blockIdx.x*4 + w;
  float di = dinv[i];
  float acc = di*di * xin[(size_t)i*HD + lane];
  int e = rowptr[i], e1 = rowptr[i+1];
  for (; e + 1 < e1; e += 2){
    int s0 = csr_src[e], s1 = csr_src[e+1];
    float n0 = csr_nrm[e], n1 = csr_nrm[e+1];
    acc += n0 * xin[(size_t)s0*HD + lane];
    acc += n1 * xin[(size_t)s1*HD + lane];
  }
  if (e < e1) acc += csr_nrm[e] * xin[(size_t)csr_src[e]*HD + lane];
  float v = acc + b2[lane];
  v = v > 0.f ? v : 0.f;
  x2b[(size_t)i*HD + lane] = bf16_rne(v);
}

// ---------------- FC + softmax, swapped-operand MFMA ----------------
__global__ __launch_bounds__(256) void k_rowsum(const ushort_t* __restrict__ x2b,
                                                const ushort_t* __restrict__ fcwp,
                                                const float* __restrict__ fcb,
                                                float* __restrict__ S){
  int lane = threadIdx.x & 63, w = threadIdx.x >> 6;
  int r = lane & 15, seg = lane >> 4;
  int row0 = blockIdx.x*128 + w*32;
  const ushort_t* xb = x2b + (size_t)(row0 + r)*HD + seg*8;
  v8s x00 = *(const v8s*)(xb);
  v8s x01 = *(const v8s*)(xb + 32);
  v8s x10 = *(const v8s*)(xb + 16*HD);
  v8s x11 = *(const v8s*)(xb + 16*HD + 32);
  float rp0 = 0.f, rp1 = 0.f;
  for (int cb=0; cb<4; ++cb){
    int colbase = blockIdx.y*256 + cb*64;
    f32x4 z = {0.f,0.f,0.f,0.f};
    f32x4 acc0[4] = {z,z,z,z}, acc1[4] = {z,z,z,z};
    #pragma unroll
    for (int nt=0; nt<4; ++nt){
      int cblk = (colbase >> 4) + nt;
      v8s bA = *(const v8s*)(fcwp + ((size_t)cblk*16 + r)*32 + seg*8);
      v8s bB = *(const v8s*)(fcwp + ((size_t)(512 + cblk)*16 + r)*32 + seg*8);
      acc0[nt] = mfma16(bA, x00, acc0[nt]);
      acc0[nt] = mfma16(bB, x01, acc0[nt]);
      acc1[nt] = mfma16(bA, x10, acc1[nt]);
      acc1[nt] = mfma16(bB, x11, acc1[nt]);
    }
    #pragma unroll
    for (int nt=0; nt<4; ++nt){
      int col = colbase + nt*16 + seg*4;
      f32x4 fb = *(const f32x4*)(fcb + col);
      #pragma unroll
      for (int j=0;j<4;++j){
        rp0 += __expf(acc0[nt][j] + fb[j]);
        rp1 += __expf(acc1[nt][j] + fb[j]);
      }
    }
  }
  rp0 += __shfl_xor(rp0, 16); rp0 += __shfl_xor(rp0, 32);
  rp1 += __shfl_xor(rp1, 16); rp1 += __shfl_xor(rp1, 32);
  if (lane < 16){
    atomicAdd(&S[row0 + lane],      rp0);
    atomicAdd(&S[row0 + 16 + lane], rp1);
  }
}

__global__ __launch_bounds__(256) void k_passB(const ushort_t* __restrict__ x2b,
                                               const ushort_t* __restrict__ fcwp,
                                               const float* __restrict__ fcb,
                                               const float* __restrict__ S,
                                               float* __restrict__ out){
  int lane = threadIdx.x & 63, w = threadIdx.x >> 6;
  int r = lane & 15, seg = lane >> 4;
  int row0 = blockIdx.x*128 + w*32;
  const ushort_t* xb = x2b + (size_t)(row0 + r)*HD + seg*8;
  v8s x00 = *(const v8s*)(xb);
  v8s x01 = *(const v8s*)(xb + 32);
  v8s x10 = *(const v8s*)(xb + 16*HD);
  v8s x11 = *(const v8s*)(xb + 16*HD + 32);
  float si0 = 1.0f / S[row0 + r];
  float si1 = 1.0f / S[row0 + 16 + r];
  float* o0 = out + (size_t)(row0 + r)*NN;
  float* o1 = out + (size_t)(row0 + 16 + r)*NN;
  for (int cb=0; cb<4; ++cb){
    int colbase = blockIdx.y*256 + cb*64;
    f32x4 z = {0.f,0.f,0.f,0.f};
    f32x4 acc0[4] = {z,z,z,z}, acc1[4] = {z,z,z,z};
    #pragma unroll
    for (int nt=0; nt<4; ++nt){
      int cblk = (colbase >> 4) + nt;
      v8s bA = *(const v8s*)(fcwp + ((size_t)cblk*16 + r)*32 + seg*8);
      v8s bB = *(const v8s*)(fcwp + ((size_t)(512 + cblk)*16 + r)*32 + seg*8);
      acc0[nt] = mfma16(bA, x00, acc0[nt]);
      acc0[nt] = mfma16(bB, x01, acc0[nt]);
      acc1[nt] = mfma16(bA, x10, acc1[nt]);
      acc1[nt] = mfma16(bB, x11, acc1[nt]);
    }
    #pragma unroll
    for (int nt=0; nt<4; ++nt){
      int col = colbase + nt*16 + seg*4;
      f32x4 fb = *(const f32x4*)(fcb + col);
      f32x4 v0, v1;
      #pragma unroll
      for (int j=0;j<4;++j){
        v0[j] = __expf(acc0[nt][j] + fb[j]) * si0;
        v1[j] = __expf(acc1[nt][j] + fb[j]) * si1;
      }
      *(f32x4*)(o0 + col) = v0;
      *(f32x4*)(o1 + col) = v1;
    }
  }
}

// ---------------- host ----------------
extern "C" void kernel_launch(void* const* d_in, const int* in_sizes, int n_in,
                              void* d_out, int out_size, void* d_ws, size_t ws_size,
                              hipStream_t stream){
  (void)in_sizes; (void)n_in; (void)out_size; (void)ws_size;
  const int*   ei  = (const int*)  d_in[0];
  const float* ew  = (const float*)d_in[1];
  const float* X   = (const float*)d_in[2];
  const float* W1  = (const float*)d_in[3];
  const float* b1  = (const float*)d_in[4];
  const float* W2  = (const float*)d_in[5];
  const float* b2  = (const float*)d_in[6];
  const float* fcW = (const float*)d_in[7];
  const float* fcb = (const float*)d_in[8];
  float* out = (float*)d_out;
  char*  ws  = (char*)d_ws;

  float*    deg     = (float*)   (ws + 0);
  float*    dinv    = (float*)   (ws + 32768);
  int*      cnt     = (int*)     (ws + 65536);
  int*      wcnt    = (int*)     (ws + 98304);
  int*      rowptr  = (int*)     (ws + 131072);
  int*      csr_src = (int*)     (ws + 167936);
  float*    csr_nrm = (float*)   (ws + 1216512);
  ushort_t* w1hi    = (ushort_t*)(ws + 2265088);
  ushort_t* w1lo    = (ushort_t*)(ws + 3313664);
  ushort_t* fcwp    = (ushort_t*)(ws + 4362240);
  float*    xw1p    = (float*)   (ws + 5410816);   // NKC * 2 MB = 16 MB
  float*    xw1     = (float*)   (ws + 22188032);
  float*    x2w     = (float*)   (ws + 24285184);
  ushort_t* x2b     = (ushort_t*)(ws + 26382336);
  float*    S       = (float*)   (ws + 27430912);

  k_prep0   <<<2048, 256, 0, stream>>>(W1, fcW, w1hi, w1lo, fcwp, deg, cnt, wcnt, S);
  k_deg_cnt <<<1024, 256, 0, stream>>>(ei, ew, deg, cnt);
  k_scan    <<<1,    256, 0, stream>>>(cnt, deg, rowptr, dinv);
  k_fill    <<<1024, 256, 0, stream>>>(ei, ew, dinv, rowptr, wcnt, csr_src, csr_nrm);
  k_gemm1   <<<dim3(128, NKC), 128, 0, stream>>>(X, w1hi, w1lo, xw1p);
  k_red     <<<512,  256, 0, stream>>>(xw1p, xw1);
  k_agg1c   <<<2048, 256, 0, stream>>>(xw1, b1, W2, dinv, rowptr, csr_src, csr_nrm, x2w);
  k_agg2    <<<2048, 256, 0, stream>>>(x2w, b2, dinv, rowptr, csr_src, csr_nrm, x2b);
  k_rowsum  <<<dim3(64,32), 256, 0, stream>>>(x2b, fcwp, fcb, S);
  k_passB   <<<dim3(64,32), 256, 0, stream>>>(x2b, fcwp, fcb, S, out);
}